// Round 6
// baseline (144.957 us; speedup 1.0000x reference)
//
#include <hip/hip_runtime.h>
#include <hip/hip_bf16.h>

// Sizes fixed by the problem
#define BATCH 4
#define NSEQ  1024
#define DIM   768
#define NH    12
#define NKV   4
#define HD    64
#define NTOK  (BATCH*NSEQ)   // 4096

using bf16 = __hip_bfloat16;
typedef __attribute__((ext_vector_type(8))) short short8;
typedef __attribute__((ext_vector_type(4))) float floatx4;
typedef __attribute__((ext_vector_type(4))) unsigned uint4v;

__device__ __forceinline__ float b2f(short x) {
  unsigned u = ((unsigned)(unsigned short)x) << 16;
  return __builtin_bit_cast(float, u);
}
__device__ __forceinline__ unsigned short f2b(float f) {
  unsigned u = __builtin_bit_cast(unsigned, f);
  unsigned r = u + 0x7FFF + ((u >> 16) & 1);   // RNE
  return (unsigned short)(r >> 16);
}
// packed f32x2 -> bf16x2 (RNE), single VALU op. lo -> bits[15:0], hi -> [31:16]
__device__ __forceinline__ unsigned cvtpk(float lo, float hi) {
  unsigned r;
  asm("v_cvt_pk_bf16_f32 %0, %1, %2" : "=v"(r) : "v"(lo), "v"(hi));
  return r;
}

// async global->LDS, 16B per lane; LDS dest = wave-uniform base + lane*16
__device__ __forceinline__ void load_lds_16(const bf16* g, bf16* l) {
  __builtin_amdgcn_global_load_lds(
      (const __attribute__((address_space(1))) void*)g,
      (__attribute__((address_space(3))) void*)l, 16, 0, 0);
}

// ---------------------------------------------------------------------------
// Fused f32->bf16 convert of all 6 input tensors (exact sizes hardcoded).
// ---------------------------------------------------------------------------
__global__ __launch_bounds__(256) void cvt_all(
    const float* __restrict__ x,  const float* __restrict__ wq,
    const float* __restrict__ wk, const float* __restrict__ wv1,
    const float* __restrict__ wv2, const float* __restrict__ wo,
    bf16* __restrict__ xb,  bf16* __restrict__ wqb, bf16* __restrict__ wkb,
    bf16* __restrict__ wv1b, bf16* __restrict__ wv2b, bf16* __restrict__ wob)
{
  int i = blockIdx.x * 256 + threadIdx.x;   // float4 index, total 1425408
  const float* s; bf16* d; int off;
  if      (i <  786432) { s = x;   d = xb;   off = i; }
  else if (i < 1081344) { s = wq;  d = wqb;  off = i -  786432; }
  else if (i < 1179648) { s = wk;  d = wkb;  off = i - 1081344; }
  else if (i < 1228800) { s = wv1; d = wv1b; off = i - 1179648; }
  else if (i < 1277952) { s = wv2; d = wv2b; off = i - 1228800; }
  else                  { s = wo;  d = wob;  off = i - 1277952; }
  float4 f = reinterpret_cast<const float4*>(s)[off];
  ushort4 u;
  u.x = f2b(f.x); u.y = f2b(f.y); u.z = f2b(f.z); u.w = f2b(f.w);
  reinterpret_cast<ushort4*>(d)[off] = u;
}

// ---------------------------------------------------------------------------
// Fused QKV projection GEMM, 128x128 tile, BK=64 (R12: halves the per-step
// vmcnt(0)+barrier drains vs BK=32 — 12 steps x 32 MFMA instead of 24 x 16).
// LDS 32 KB. Both-sides XOR swizzle (rule 21): linear global_load_lds dest +
// XOR-permuted per-lane GLOBAL source + XOR on the hoisted ds_read addrs.
// grid = (20 N-tiles, 32 M-tiles). N-tiles 0-11: q (rope+norm -> PACKED Qpk),
// 12-15: k (-> PACKED Kpk), 16-17: v1, 18-19: v2 (-> packed Vpk).
// R16: V tiles stored with key-permutation pi(key = kt*16+Q*4+r) =
// slot Q*8 + kt*4 + r — makes attn's PV A-fragment the lane's OWN cvt_pk
// registers (zero cross-lane redistribution; O is invariant under a common
// permutation of P-key order and V-row order).
// R11 epilogue diet retained. Epilogue rule: no pointer-arg calls (R4 bug).
// ---------------------------------------------------------------------------
__global__ __launch_bounds__(256, 2) void gemm_qkv(
    const bf16* __restrict__ xb,
    const bf16* __restrict__ Wqb, const bf16* __restrict__ Wkb,
    const bf16* __restrict__ Wv1b, const bf16* __restrict__ Wv2b,
    bf16* __restrict__ Qpk, bf16* __restrict__ Kpk,
    bf16* __restrict__ Vpk1, bf16* __restrict__ Vpk2)
{
  __shared__ __align__(16) bf16 As[128 * 64];
  __shared__ __align__(16) bf16 Ws[128 * 64];

  const int bn = blockIdx.x, bm = blockIdx.y;
  const bf16* Wp;
  if (bn < 12)      Wp = Wqb  + (size_t)bn * 128 * 768;
  else if (bn < 16) Wp = Wkb  + (size_t)(bn - 12) * 128 * 768;
  else if (bn < 18) Wp = Wv1b + (size_t)(bn - 16) * 128 * 768;
  else              Wp = Wv2b + (size_t)(bn - 18) * 128 * 768;

  const int t = threadIdx.x, wave = t >> 6, lane = t & 63;
  const int wm = wave >> 1, wn = wave & 1;
  const int quad = lane >> 4, lr = lane & 15;

  // staging: wave stages 32 rows per tile as 4 chunks of 8 rows x 64 cols.
  // chunk row = wave*32 + c*8 + (lane>>3)  (row&7 == lane>>3), source col
  // group XOR'ed with row&7 so linear LDS dest lands swizzled.
  const int srow = wave * 32 + (lane >> 3);
  const int scol = ((lane & 7) ^ (lane >> 3)) * 8;
  const bf16* Ag = xb + (size_t)(bm * 128 + srow) * 768 + scol;
  const bf16* Wg = Wp + (size_t)srow * 768 + scol;
  bf16* Al = As + wave * 32 * 64;
  bf16* Wl = Ws + wave * 32 * 64;

  floatx4 acc[4][4] = {};

  for (int k0 = 0; k0 < 768; k0 += 64) {
    #pragma unroll
    for (int c = 0; c < 4; ++c) {
      load_lds_16(Ag + (size_t)c * 8 * 768 + k0, Al + c * 8 * 64);
      load_lds_16(Wg + (size_t)c * 8 * 768 + k0, Wl + c * 8 * 64);
    }
    __syncthreads();

    short8 af[4][2], wf[4][2];
    #pragma unroll
    for (int mt = 0; mt < 4; ++mt)
      #pragma unroll
      for (int ks = 0; ks < 2; ++ks)
        af[mt][ks] = *reinterpret_cast<const short8*>(
            &As[(wm * 64 + mt * 16 + lr) * 64 + ((ks * 32 + quad * 8) ^ ((lr & 7) * 8))]);
    #pragma unroll
    for (int nt = 0; nt < 4; ++nt)
      #pragma unroll
      for (int ks = 0; ks < 2; ++ks)
        wf[nt][ks] = *reinterpret_cast<const short8*>(
            &Ws[(wn * 64 + nt * 16 + lr) * 64 + ((ks * 32 + quad * 8) ^ ((lr & 7) * 8))]);

    #pragma unroll
    for (int mt = 0; mt < 4; ++mt)
      #pragma unroll
      for (int nt = 0; nt < 4; ++nt) {
        acc[mt][nt] = __builtin_amdgcn_mfma_f32_16x16x32_bf16(af[mt][0], wf[nt][0], acc[mt][nt], 0, 0, 0);
        acc[mt][nt] = __builtin_amdgcn_mfma_f32_16x16x32_bf16(af[mt][1], wf[nt][1], acc[mt][nt], 0, 0, 0);
      }
    __syncthreads();
  }

  // Epilogues. C/D: row = bm*128 + wm*64 + mt*16 + quad*4 + r,
  //                 col(within 128-tile) = wn*64 + nt*16 + lr
  if (bn < 16) {
    const float K2 = 0.41524101186098309f;             // log2(10000)/32
    const float invf0 = exp2f(-(float)lr * K2);
    const float invf1 = exp2f(-(float)(16 + lr) * K2);
    const float sgn = (lr & 1) ? 1.f : -1.f;
    const bool isq = (bn < 12);
    const int hq = bn * 2 + wn;                        // 0..23 (q)
    const int sq_ = hq / 12, hq_ = hq % 12;
    const int hh = (bn - 12) * 2 + wn;                 // 0..7 (k)
    const int sk_ = hh >> 2, kvh_ = hh & 3;
    const int qk128 = (lr >> 3) * 128;
    #pragma unroll
    for (int mt = 0; mt < 4; ++mt) {
      // row group is 4-aligned -> n>>5, row>>10 constant across r (no cross)
      const int row0 = bm * 128 + wm * 64 + mt * 16 + quad * 4;
      const int n0 = row0 & (NSEQ - 1);
      const int bb = row0 >> 10, kh = n0 >> 5;
      const float ph = (float)kh;
      const float pw0 = (float)(n0 & 31);
      const float t0 = ph * invf0, t1 = ph * invf1;
      const float c0 = __cosf(t0), s0 = __sinf(t0);
      const float c1 = __cosf(t1), s1 = __sinf(t1);
      bf16* tb0;
      if (isq) {
        tb0 = Qpk + ((size_t)((bb * 2 + sq_) * 12 + hq_) * 32 + kh) * 2048
              + (size_t)(mt & 1) * 1024 + qk128 + (quad * 4) * 8 + (lr & 7);
      } else {
        tb0 = Kpk + ((size_t)((bb * 2 + sk_) * 4 + kvh_) * 32 + kh) * 2048
              + (size_t)(mt & 1) * 1024 + qk128 + (quad * 4) * 8 + (lr & 7);
      }
      #pragma unroll
      for (int r = 0; r < 4; ++r) {
        float v0 = acc[mt][0][r];
        float v1 = acc[mt][1][r];
        float v2 = acc[mt][2][r];
        float v3 = acc[mt][3][r];
        float rot0 = sgn * __shfl_xor(v0, 1);
        float rot1 = sgn * __shfl_xor(v1, 1);
        float rot2 = sgn * __shfl_xor(v2, 1);
        float rot3 = sgn * __shfl_xor(v3, 1);
        float pw = pw0 + (float)r;
        float t2 = pw * invf0, t3 = pw * invf1;
        float rv0 = v0 * c0 + rot0 * s0;
        float rv1 = v1 * c1 + rot1 * s1;
        float rv2 = v2 * __cosf(t2) + rot2 * __sinf(t2);
        float rv3 = v3 * __cosf(t3) + rot3 * __sinf(t3);
        float ss = rv0 * rv0 + rv1 * rv1 + rv2 * rv2 + rv3 * rv3;
        #pragma unroll
        for (int off = 1; off < 16; off <<= 1) ss += __shfl_xor(ss, off);
        float sc = 1.f / (sqrtf(ss) + 1e-6f);
        if (isq) sc *= 0.18033688011112042f;           // log2(e)/8 folded into Q
        bf16* tb = tb0 + r * 8;
        unsigned pkA = cvtpk(rv0 * sc, rv1 * sc);
        unsigned pkB = cvtpk(rv2 * sc, rv3 * sc);
        *(unsigned short*)&tb[0]   = (unsigned short)pkA;
        *(unsigned short*)&tb[256] = (unsigned short)(pkA >> 16);
        *(unsigned short*)&tb[512] = (unsigned short)pkB;
        *(unsigned short*)&tb[768] = (unsigned short)(pkB >> 16);
      }
    }
  } else {
    const bool is2 = (bn >= 18);
    bf16* Vp = is2 ? Vpk2 : Vpk1;
    const int kvh_ = (bn - (is2 ? 18 : 16)) * 2 + wn;  // 0..3
    #pragma unroll
    for (int mt = 0; mt < 4; ++mt)
      #pragma unroll
      for (int r = 0; r < 4; ++r) {
        int row = bm * 128 + wm * 64 + mt * 16 + quad * 4 + r;
        int n = row & (NSEQ - 1);
        int bb = row >> 10, kh = n >> 5;
        int rowm = (mt & 1) * 16 + quad * 4 + r;       // key index in 32-tile
        // R16 pi-permuted slot: key = kt*16 + Q*4 + rr -> slot Q*8 + kt*4 + rr
        int quad_v = (rowm >> 2) & 3;
        int j = ((rowm >> 4) << 2) | (rowm & 3);
        bf16* tb = Vp + ((size_t)(bb * 4 + kvh_) * 32 + kh) * 2048
                   + quad_v * 128 + lr * 8 + j;
        unsigned pkA = cvtpk(acc[mt][0][r], acc[mt][1][r]);
        unsigned pkB = cvtpk(acc[mt][2][r], acc[mt][3][r]);
        *(unsigned short*)&tb[0]    = (unsigned short)pkA;
        *(unsigned short*)&tb[512]  = (unsigned short)(pkA >> 16);
        *(unsigned short*)&tb[1024] = (unsigned short)pkB;
        *(unsigned short*)&tb[1536] = (unsigned short)(pkB >> 16);
      }
  }
}

// ---------------------------------------------------------------------------
// Final GEMM: out = X @ Wo^T + bo, f32 out. 64x64 tiles, grid (12,64) = 768
// blocks = 3 blocks/CU. R12 BK=64 version (R14's BK=128 regressed +1 µs).
// 16 KB LDS, both-sides XOR swizzle as gemm_qkv.
// ---------------------------------------------------------------------------
__global__ __launch_bounds__(256) void gemm_out(
    const bf16* __restrict__ Xb, const bf16* __restrict__ Wob,
    float* __restrict__ out, const float* __restrict__ bias)
{
  __shared__ __align__(16) bf16 As[64 * 64];
  __shared__ __align__(16) bf16 Ws[64 * 64];

  const int bn = blockIdx.x, bm = blockIdx.y;
  const int t = threadIdx.x, wave = t >> 6, lane = t & 63;
  const int wm = wave >> 1, wn = wave & 1;
  const int quad = lane >> 4, lr = lane & 15;

  // staging: wave stages 16 rows per tile as 2 chunks of 8 rows x 64 cols,
  // source col group XOR'ed with row&7 (== lane>>3).
  const int srow = wave * 16 + (lane >> 3);
  const int scol = ((lane & 7) ^ (lane >> 3)) * 8;
  const bf16* Ag = Xb  + (size_t)(bm * 64 + srow) * 768 + scol;
  const bf16* Wg = Wob + (size_t)(bn * 64 + srow) * 768 + scol;
  bf16* Al = As + wave * 16 * 64;
  bf16* Wl = Ws + wave * 16 * 64;

  floatx4 acc[2][2] = {};

  for (int k0 = 0; k0 < 768; k0 += 64) {
    #pragma unroll
    for (int c = 0; c < 2; ++c) {
      load_lds_16(Ag + (size_t)c * 8 * 768 + k0, Al + c * 8 * 64);
      load_lds_16(Wg + (size_t)c * 8 * 768 + k0, Wl + c * 8 * 64);
    }
    __syncthreads();

    short8 af[2][2], wf[2][2];
    #pragma unroll
    for (int mt = 0; mt < 2; ++mt)
      #pragma unroll
      for (int ks = 0; ks < 2; ++ks)
        af[mt][ks] = *reinterpret_cast<const short8*>(
            &As[(wm * 32 + mt * 16 + lr) * 64 + ((ks * 32 + quad * 8) ^ ((lr & 7) * 8))]);
    #pragma unroll
    for (int nt = 0; nt < 2; ++nt)
      #pragma unroll
      for (int ks = 0; ks < 2; ++ks)
        wf[nt][ks] = *reinterpret_cast<const short8*>(
            &Ws[(wn * 32 + nt * 16 + lr) * 64 + ((ks * 32 + quad * 8) ^ ((lr & 7) * 8))]);

    #pragma unroll
    for (int mt = 0; mt < 2; ++mt)
      #pragma unroll
      for (int nt = 0; nt < 2; ++nt) {
        acc[mt][nt] = __builtin_amdgcn_mfma_f32_16x16x32_bf16(af[mt][0], wf[nt][0], acc[mt][nt], 0, 0, 0);
        acc[mt][nt] = __builtin_amdgcn_mfma_f32_16x16x32_bf16(af[mt][1], wf[nt][1], acc[mt][nt], 0, 0, 0);
      }
    __syncthreads();
  }

  #pragma unroll
  for (int nt = 0; nt < 2; ++nt) {
    int col = bn * 64 + wn * 32 + nt * 16 + lr;
    float bv = bias[col];
    #pragma unroll
    for (int mt = 0; mt < 2; ++mt)
      #pragma unroll
      for (int r = 0; r < 4; ++r) {
        int row = bm * 64 + wm * 32 + mt * 16 + quad * 4 + r;
        out[(size_t)row * 768 + col] = acc[mt][nt][r] + bv;
      }
  }
}

// ---------------------------------------------------------------------------
// MFMA flash attention. R15: swapped QK^T (St = mfma(K,Q)) put P in
// registers. R16: ZERO-SHUFFLE PV — V tiles are pre-permuted (pi) at pack
// time so the PV A-fragment is the lane's own cvt_pk registers in order
// {pk[0][mt][0], pk[0][mt][1], pk[1][mt][0], pk[1][mt][1]} (verified: A-slot
// j needs key (j>=4?16:0)+quad*4+(j&3) = exactly what the lane holds).
// Window mask folded into the MFMA accumulator init (Sinit = 0 / -1e38,
// loop-invariant): removes 16 cndmask/step; exp2(-1e38+|S|<=11) == 0.
// Per-step cross-lane/select ops: 20 -> 0. R9 4-wave structure unchanged.
// ---------------------------------------------------------------------------
struct Frag { short8 kf[2][2]; short8 vf[4]; };

__device__ __forceinline__ void attn_load(
    Frag& f, const bf16* __restrict__ kp, const bf16* __restrict__ vp,
    int kh, int lane8)
{
  const bf16* kt = kp + (size_t)kh * 2048 + lane8;
  const bf16* vt = vp + (size_t)kh * 2048 + lane8;
  f.kf[0][0] = *reinterpret_cast<const short8*>(kt);
  f.kf[0][1] = *reinterpret_cast<const short8*>(kt + 512);
  f.kf[1][0] = *reinterpret_cast<const short8*>(kt + 1024);
  f.kf[1][1] = *reinterpret_cast<const short8*>(kt + 1536);
  f.vf[0] = *reinterpret_cast<const short8*>(vt);
  f.vf[1] = *reinterpret_cast<const short8*>(vt + 512);
  f.vf[2] = *reinterpret_cast<const short8*>(vt + 1024);
  f.vf[3] = *reinterpret_cast<const short8*>(vt + 1536);
}

__device__ __forceinline__ void attn_step(
    const short8 (&qf)[2][2], const Frag& f, const floatx4 (&Sinit)[2][2],
    floatx4 (&O)[2][4], float (&psum)[2])
{
  // Swapped: St[kt][mt] = K_kt * Q_mt^T -> D[key-local][q-local].
  // Mask pre-loaded into the accumulator (0 or -1e38).
  floatx4 St[2][2] = {{Sinit[0][0], Sinit[0][1]}, {Sinit[1][0], Sinit[1][1]}};
  #pragma unroll
  for (int ks = 0; ks < 2; ++ks) {
    St[0][0] = __builtin_amdgcn_mfma_f32_16x16x32_bf16(f.kf[0][ks], qf[0][ks], St[0][0], 0, 0, 0);
    St[0][1] = __builtin_amdgcn_mfma_f32_16x16x32_bf16(f.kf[0][ks], qf[1][ks], St[0][1], 0, 0, 0);
    St[1][0] = __builtin_amdgcn_mfma_f32_16x16x32_bf16(f.kf[1][ks], qf[0][ks], St[1][0], 0, 0, 0);
    St[1][1] = __builtin_amdgcn_mfma_f32_16x16x32_bf16(f.kf[1][ks], qf[1][ks], St[1][1], 0, 0, 0);
  }

  // softmax weights (S carries 0.125*log2(e) via Q pack): weight = exp2(S);
  // masked entries are exp2(-1e38) = 0 exactly.
  unsigned pk[2][2][2];
  #pragma unroll
  for (int kt = 0; kt < 2; ++kt)
    #pragma unroll
    for (int mt = 0; mt < 2; ++mt) {
      float pr[4];
      #pragma unroll
      for (int r = 0; r < 4; ++r) {
        float p = __builtin_amdgcn_exp2f(St[kt][mt][r]);
        psum[mt] += p;
        pr[r] = p;
      }
      pk[kt][mt][0] = cvtpk(pr[0], pr[1]);
      pk[kt][mt][1] = cvtpk(pr[2], pr[3]);
    }

  // PV A-frag: with pi-permuted V rows, A-slot j = key (j>=4?16:0)+quad*4+(j&3)
  // -> the lane's own pk registers, in order. Zero cross-lane ops.
  #pragma unroll
  for (int mt = 0; mt < 2; ++mt) {
    uint4v regs;
    regs[0] = pk[0][mt][0];
    regs[1] = pk[0][mt][1];
    regs[2] = pk[1][mt][0];
    regs[3] = pk[1][mt][1];
    short8 pa = __builtin_bit_cast(short8, regs);
    #pragma unroll
    for (int ntd = 0; ntd < 4; ++ntd)
      O[mt][ntd] = __builtin_amdgcn_mfma_f32_16x16x32_bf16(pa, f.vf[ntd], O[mt][ntd], 0, 0, 0);
  }
}

__global__ __launch_bounds__(256, 2) void attn_mfma(
    const bf16* __restrict__ Qpk, const bf16* __restrict__ Kpk,
    const bf16* __restrict__ Vpk1, const bf16* __restrict__ Vpk2,
    const float* __restrict__ lambda_p, bf16* __restrict__ X)
{
  // Combine phase: slabA [0,10240) = O 8192 + psum (stream 0)
  //                slabB [10240,20480)                (stream 1)
  //                Xs [0,4608) after B3 (slabA dead by then)
  __shared__ __align__(16) char smem[20480];

  const int bid = blockIdx.x;
  const int qh = bid & 31;
  const int hb = bid >> 5;          // h + 12*b
  const int h  = hb % 12;
  const int b  = hb / 12;
  const int kvh = h / 3;

  const int t = threadIdx.x;
  const int w = t >> 6;             // 0..3
  const int s = w >> 1;             // stream
  const int half = w & 1;           // kh half
  const int lane = t & 63;
  const int quad = lane >> 4, lr = lane & 15;
  const int lane8 = lane * 8;

  float* myO = (float*)(smem + (s ? 10240 : 0));        // this stream's slab
  float* myP = (float*)(smem + (s ? 10240 : 0) + 8192);
  bf16* Xs = (bf16*)smem;                               // [32][72] bf16

  const int tok0 = b * NSEQ + qh * 32;

  // Q fragments: coalesced from packed tiles
  short8 qf[2][2];
  {
    const bf16* qt = Qpk + ((size_t)((b * 2 + s) * 12 + h) * 32 + qh) * 2048 + lane8;
    qf[0][0] = *reinterpret_cast<const short8*>(qt);
    qf[0][1] = *reinterpret_cast<const short8*>(qt + 512);
    qf[1][0] = *reinterpret_cast<const short8*>(qt + 1024);
    qf[1][1] = *reinterpret_cast<const short8*>(qt + 1536);
  }

  // window mask folded into MFMA acc init (swapped layout):
  // key w = kt*16+quad*4+r, q w = mt*16+lr; masked iff |dw| > 8.
  floatx4 Sinit[2][2];
  #pragma unroll
  for (int kt = 0; kt < 2; ++kt)
    #pragma unroll
    for (int mt = 0; mt < 2; ++mt)
      #pragma unroll
      for (int r = 0; r < 4; ++r) {
        int wk = kt * 16 + quad * 4 + r;
        int wq = mt * 16 + lr;
        int d = wk - wq; if (d < 0) d = -d;
        Sinit[kt][mt][r] = (d <= 8) ? 0.0f : -1e38f;
      }

  floatx4 O[2][4] = {};
  float psum[2] = {};

  const int kh0 = (qh > 8) ? qh - 8 : 0;
  const int kh1 = (qh < 23) ? qh + 8 : 31;
  const int cnt = kh1 - kh0 + 1;              // 9..17 -> both halves nonempty
  const int cA = (cnt + 1) >> 1;
  const int khA = half ? kh0 + cA : kh0;
  const int khB = half ? kh1 : kh0 + cA - 1;

  const bf16* kpbase = Kpk + (size_t)((b * 2 + s) * 4 + kvh) * 32 * 2048;
  const bf16* vpbase = (s ? Vpk2 : Vpk1) + (size_t)(b * 4 + kvh) * 32 * 2048;

  Frag fA, fB;
  attn_load(fA, kpbase, vpbase, khA, lane8);
  attn_load(fB, kpbase, vpbase, (khA + 1 <= khB) ? khA + 1 : khB, lane8);

  int i = khA;
  while (true) {
    attn_step(qf, fA, Sinit, O, psum);
    if (i == khB) break;
    ++i;
    attn_load(fA, kpbase, vpbase, (i + 1 <= khB) ? i + 1 : i, lane8);
    attn_step(qf, fB, Sinit, O, psum);
    if (i == khB) break;
    ++i;
    attn_load(fB, kpbase, vpbase, (i + 1 <= khB) ? i + 1 : i, lane8);
  }

  // ---- parallel two-stream combine (each stream in its own slab) ----
  auto writeslab = [&]() {
    #pragma unroll
    for (int mt = 0; mt < 2; ++mt)
      #pragma unroll
      for (int ntd = 0; ntd < 4; ++ntd)
        *reinterpret_cast<floatx4*>(&myO[(mt * 4 + ntd) * 256 + lane * 4]) = O[mt][ntd];
    myP[lane]      = psum[0];
    myP[64 + lane] = psum[1];
  };
  auto readadd_norm = [&]() {
    #pragma unroll
    for (int mt = 0; mt < 2; ++mt)
      #pragma unroll
      for (int ntd = 0; ntd < 4; ++ntd)
        O[mt][ntd] += *reinterpret_cast<const floatx4*>(&myO[(mt * 4 + ntd) * 256 + lane * 4]);
    psum[0] += myP[lane];
    psum[1] += myP[64 + lane];
    // cross-quad reduce: lanes {l, l^16, l^32, l^48} hold the 4 quad partials
    // for q = mt*16 + lr -> after xor16+xor32, fully reduced and replicated.
    #pragma unroll
    for (int mt = 0; mt < 2; ++mt) {
      psum[mt] += __shfl_xor(psum[mt], 16);
      psum[mt] += __shfl_xor(psum[mt], 32);
      psum[mt] = 1.f / psum[mt];
    }
    // remap inverse onto O rows (q = mt*16 + quad*4 + r): fetch from the
    // lane in own quad with lr' = quad*4 + r (value replicated over quads).
    #pragma unroll
    for (int mt = 0; mt < 2; ++mt) {
      float invq[4];
      #pragma unroll
      for (int r = 0; r < 4; ++r)
        invq[r] = __shfl(psum[mt], (lane & 48) + quad * 4 + r);
      #pragma unroll
      for (int ntd = 0; ntd < 4; ++ntd)
        #pragma unroll
        for (int r = 0; r < 4; ++r)
          O[mt][ntd][r] *= invq[r];
    }
  };

  __syncthreads();                       // B1: loop done
  if (half) writeslab();                 // w1 -> slabA, w3 -> slabB
  __syncthreads();                       // B2
  if (!half) {
    readadd_norm();                      // w0: stream0 total; w2: stream1 total
    if (s) {                             // w2 publishes normalized O2
      #pragma unroll
      for (int mt = 0; mt < 2; ++mt)
        #pragma unroll
        for (int ntd = 0; ntd < 4; ++ntd)
          *reinterpret_cast<floatx4*>(&myO[(mt * 4 + ntd) * 256 + lane * 4]) = O[mt][ntd];
    }
  }
  __syncthreads();                       // B3
  if (w == 0) {                          // differential combine -> Xs
    const float* O2s = (const float*)(smem + 10240);
    float lam = log1pf(__expf(lambda_p[h]));
    #pragma unroll
    for (int mt = 0; mt < 2; ++mt)
      #pragma unroll
      for (int ntd = 0; ntd < 4; ++ntd) {
        floatx4 o2 = *reinterpret_cast<const floatx4*>(&O2s[(mt * 4 + ntd) * 256 + lane * 4]);
        #pragma unroll
        for (int r = 0; r < 4; ++r) {
          float xv = O[mt][ntd][r] - lam * o2[r];
          *(unsigned short*)&Xs[(mt * 16 + quad * 4 + r) * 72 + ntd * 16 + lr] = f2b(xv);
        }
      }
  }
  __syncthreads();                       // B4

  // coalesced store of the 32x64 bf16 tile (256 thr = 32 rows x 8 segs)
  {
    int row = t >> 3, seg = t & 7;
    short8 xv = *reinterpret_cast<const short8*>(&Xs[row * 72 + seg * 8]);
    *reinterpret_cast<short8*>(X + (size_t)(tok0 + row) * 768 + h * 64 + seg * 8) = xv;
  }
}

// ---------------------------------------------------------------------------
extern "C" void kernel_launch(void* const* d_in, const int* in_sizes, int n_in,
                              void* d_out, int out_size, void* d_ws, size_t ws_size,
                              hipStream_t stream)
{
  const float* x        = (const float*)d_in[0];
  const float* Wq       = (const float*)d_in[1];
  const float* Wk       = (const float*)d_in[2];
  const float* Wv1      = (const float*)d_in[3];
  const float* Wv2      = (const float*)d_in[4];
  const float* lambda_p = (const float*)d_in[5];
  const float* Wo       = (const float*)d_in[6];
  const float* bo       = (const float*)d_in[7];
  float* out = (float*)d_out;

  bf16* xb   = (bf16*)d_ws;                      // 4096*768
  bf16* Wqb  = xb   + (size_t)NTOK * 768;        // 1536*768
  bf16* Wkb  = Wqb  + (size_t)1536 * 768;        // 512*768
  bf16* Wv1b = Wkb  + (size_t)512 * 768;         // 256*768
  bf16* Wv2b = Wv1b + (size_t)256 * 768;         // 256*768
  bf16* Wob  = Wv2b + (size_t)256 * 768;         // 768*768
  bf16* Qpk  = Wob  + (size_t)768 * 768;         // 3072 tiles * 2048
  bf16* Xb   = Qpk  + (size_t)NTOK * 1536;       // 4096*768
  bf16* Vpk1 = Xb   + (size_t)NTOK * 768;        // 512 tiles * 2048
  bf16* Vpk2 = Vpk1 + (size_t)512 * 2048;        // 512 tiles * 2048
  bf16* Kpk  = Vpk2 + (size_t)512 * 2048;        // 1024 tiles * 2048

  cvt_all<<<5568, 256, 0, stream>>>(x, Wq, Wk, Wv1, Wv2, Wo,
                                    xb, Wqb, Wkb, Wv1b, Wv2b, Wob);

  gemm_qkv<<<dim3(20, 32), 256, 0, stream>>>(xb, Wqb, Wkb, Wv1b, Wv2b,
                                             Qpk, Kpk, Vpk1, Vpk2);

  attn_mfma<<<BATCH * NH * 32, 256, 0, stream>>>(Qpk, Kpk, Vpk1, Vpk2, lambda_p, Xb);

  gemm_out<<<dim3(12, 64), 256, 0, stream>>>(Xb, Wob, out, bo);
}

// Round 7
// 143.205 us; speedup vs baseline: 1.0122x; 1.0122x over previous
//
#include <hip/hip_runtime.h>
#include <hip/hip_bf16.h>

// Sizes fixed by the problem
#define BATCH 4
#define NSEQ  1024
#define DIM   768
#define NH    12
#define NKV   4
#define HD    64
#define NTOK  (BATCH*NSEQ)   // 4096

using bf16 = __hip_bfloat16;
typedef __attribute__((ext_vector_type(8))) short short8;
typedef __attribute__((ext_vector_type(4))) float floatx4;
typedef __attribute__((ext_vector_type(4))) unsigned uint4v;

__device__ __forceinline__ float b2f(short x) {
  unsigned u = ((unsigned)(unsigned short)x) << 16;
  return __builtin_bit_cast(float, u);
}
__device__ __forceinline__ unsigned short f2b(float f) {
  unsigned u = __builtin_bit_cast(unsigned, f);
  unsigned r = u + 0x7FFF + ((u >> 16) & 1);   // RNE
  return (unsigned short)(r >> 16);
}
// packed f32x2 -> bf16x2 (RNE), single VALU op. lo -> bits[15:0], hi -> [31:16]
__device__ __forceinline__ unsigned cvtpk(float lo, float hi) {
  unsigned r;
  asm("v_cvt_pk_bf16_f32 %0, %1, %2" : "=v"(r) : "v"(lo), "v"(hi));
  return r;
}

// async global->LDS, 16B per lane; LDS dest = wave-uniform base + lane*16
__device__ __forceinline__ void load_lds_16(const bf16* g, bf16* l) {
  __builtin_amdgcn_global_load_lds(
      (const __attribute__((address_space(1))) void*)g,
      (__attribute__((address_space(3))) void*)l, 16, 0, 0);
}

// ---------------------------------------------------------------------------
// Fused f32->bf16 convert of all 6 input tensors (exact sizes hardcoded).
// ---------------------------------------------------------------------------
__global__ __launch_bounds__(256) void cvt_all(
    const float* __restrict__ x,  const float* __restrict__ wq,
    const float* __restrict__ wk, const float* __restrict__ wv1,
    const float* __restrict__ wv2, const float* __restrict__ wo,
    bf16* __restrict__ xb,  bf16* __restrict__ wqb, bf16* __restrict__ wkb,
    bf16* __restrict__ wv1b, bf16* __restrict__ wv2b, bf16* __restrict__ wob)
{
  int i = blockIdx.x * 256 + threadIdx.x;   // float4 index, total 1425408
  const float* s; bf16* d; int off;
  if      (i <  786432) { s = x;   d = xb;   off = i; }
  else if (i < 1081344) { s = wq;  d = wqb;  off = i -  786432; }
  else if (i < 1179648) { s = wk;  d = wkb;  off = i - 1081344; }
  else if (i < 1228800) { s = wv1; d = wv1b; off = i - 1179648; }
  else if (i < 1277952) { s = wv2; d = wv2b; off = i - 1228800; }
  else                  { s = wo;  d = wob;  off = i - 1277952; }
  float4 f = reinterpret_cast<const float4*>(s)[off];
  ushort4 u;
  u.x = f2b(f.x); u.y = f2b(f.y); u.z = f2b(f.z); u.w = f2b(f.w);
  reinterpret_cast<ushort4*>(d)[off] = u;
}

// ---------------------------------------------------------------------------
// Fused QKV projection GEMM, 128x128 tile, BK=64 (R12). LDS 32 KB.
// Both-sides XOR swizzle (rule 21). grid = (20 N-tiles, 32 M-tiles).
// N-tiles 0-11: q (rope+norm -> PACKED Qpk), 12-15: k (-> Kpk),
// 16-17: v1, 18-19: v2 (-> pi-permuted Vpk, R16).
// R17: __launch_bounds__(256,3) — 640 blocks at 2 blocks/CU = 512-capacity
// -> 1 full wave + 128-block tail on 1/4 of the machine (~37% waste).
// 3 blocks/CU (VGPR cap 170, m97-class kernel sits at 164) -> capacity 768,
// single dispatch wave, tail gone + extra latency-hiding waves.
// R11 epilogue diet retained. Epilogue rule: no pointer-arg calls (R4 bug).
// ---------------------------------------------------------------------------
__global__ __launch_bounds__(256, 3) void gemm_qkv(
    const bf16* __restrict__ xb,
    const bf16* __restrict__ Wqb, const bf16* __restrict__ Wkb,
    const bf16* __restrict__ Wv1b, const bf16* __restrict__ Wv2b,
    bf16* __restrict__ Qpk, bf16* __restrict__ Kpk,
    bf16* __restrict__ Vpk1, bf16* __restrict__ Vpk2)
{
  __shared__ __align__(16) bf16 As[128 * 64];
  __shared__ __align__(16) bf16 Ws[128 * 64];

  const int bn = blockIdx.x, bm = blockIdx.y;
  const bf16* Wp;
  if (bn < 12)      Wp = Wqb  + (size_t)bn * 128 * 768;
  else if (bn < 16) Wp = Wkb  + (size_t)(bn - 12) * 128 * 768;
  else if (bn < 18) Wp = Wv1b + (size_t)(bn - 16) * 128 * 768;
  else              Wp = Wv2b + (size_t)(bn - 18) * 128 * 768;

  const int t = threadIdx.x, wave = t >> 6, lane = t & 63;
  const int wm = wave >> 1, wn = wave & 1;
  const int quad = lane >> 4, lr = lane & 15;

  // staging: wave stages 32 rows per tile as 4 chunks of 8 rows x 64 cols.
  // chunk row = wave*32 + c*8 + (lane>>3)  (row&7 == lane>>3), source col
  // group XOR'ed with row&7 so linear LDS dest lands swizzled.
  const int srow = wave * 32 + (lane >> 3);
  const int scol = ((lane & 7) ^ (lane >> 3)) * 8;
  const bf16* Ag = xb + (size_t)(bm * 128 + srow) * 768 + scol;
  const bf16* Wg = Wp + (size_t)srow * 768 + scol;
  bf16* Al = As + wave * 32 * 64;
  bf16* Wl = Ws + wave * 32 * 64;

  floatx4 acc[4][4] = {};

  for (int k0 = 0; k0 < 768; k0 += 64) {
    #pragma unroll
    for (int c = 0; c < 4; ++c) {
      load_lds_16(Ag + (size_t)c * 8 * 768 + k0, Al + c * 8 * 64);
      load_lds_16(Wg + (size_t)c * 8 * 768 + k0, Wl + c * 8 * 64);
    }
    __syncthreads();

    short8 af[4][2], wf[4][2];
    #pragma unroll
    for (int mt = 0; mt < 4; ++mt)
      #pragma unroll
      for (int ks = 0; ks < 2; ++ks)
        af[mt][ks] = *reinterpret_cast<const short8*>(
            &As[(wm * 64 + mt * 16 + lr) * 64 + ((ks * 32 + quad * 8) ^ ((lr & 7) * 8))]);
    #pragma unroll
    for (int nt = 0; nt < 4; ++nt)
      #pragma unroll
      for (int ks = 0; ks < 2; ++ks)
        wf[nt][ks] = *reinterpret_cast<const short8*>(
            &Ws[(wn * 64 + nt * 16 + lr) * 64 + ((ks * 32 + quad * 8) ^ ((lr & 7) * 8))]);

    #pragma unroll
    for (int mt = 0; mt < 4; ++mt)
      #pragma unroll
      for (int nt = 0; nt < 4; ++nt) {
        acc[mt][nt] = __builtin_amdgcn_mfma_f32_16x16x32_bf16(af[mt][0], wf[nt][0], acc[mt][nt], 0, 0, 0);
        acc[mt][nt] = __builtin_amdgcn_mfma_f32_16x16x32_bf16(af[mt][1], wf[nt][1], acc[mt][nt], 0, 0, 0);
      }
    __syncthreads();
  }

  // Epilogues. C/D: row = bm*128 + wm*64 + mt*16 + quad*4 + r,
  //                 col(within 128-tile) = wn*64 + nt*16 + lr
  if (bn < 16) {
    const float K2 = 0.41524101186098309f;             // log2(10000)/32
    const float invf0 = exp2f(-(float)lr * K2);
    const float invf1 = exp2f(-(float)(16 + lr) * K2);
    const float sgn = (lr & 1) ? 1.f : -1.f;
    const bool isq = (bn < 12);
    const int hq = bn * 2 + wn;                        // 0..23 (q)
    const int sq_ = hq / 12, hq_ = hq % 12;
    const int hh = (bn - 12) * 2 + wn;                 // 0..7 (k)
    const int sk_ = hh >> 2, kvh_ = hh & 3;
    const int qk128 = (lr >> 3) * 128;
    #pragma unroll
    for (int mt = 0; mt < 4; ++mt) {
      // row group is 4-aligned -> n>>5, row>>10 constant across r (no cross)
      const int row0 = bm * 128 + wm * 64 + mt * 16 + quad * 4;
      const int n0 = row0 & (NSEQ - 1);
      const int bb = row0 >> 10, kh = n0 >> 5;
      const float ph = (float)kh;
      const float pw0 = (float)(n0 & 31);
      const float t0 = ph * invf0, t1 = ph * invf1;
      const float c0 = __cosf(t0), s0 = __sinf(t0);
      const float c1 = __cosf(t1), s1 = __sinf(t1);
      bf16* tb0;
      if (isq) {
        tb0 = Qpk + ((size_t)((bb * 2 + sq_) * 12 + hq_) * 32 + kh) * 2048
              + (size_t)(mt & 1) * 1024 + qk128 + (quad * 4) * 8 + (lr & 7);
      } else {
        tb0 = Kpk + ((size_t)((bb * 2 + sk_) * 4 + kvh_) * 32 + kh) * 2048
              + (size_t)(mt & 1) * 1024 + qk128 + (quad * 4) * 8 + (lr & 7);
      }
      #pragma unroll
      for (int r = 0; r < 4; ++r) {
        float v0 = acc[mt][0][r];
        float v1 = acc[mt][1][r];
        float v2 = acc[mt][2][r];
        float v3 = acc[mt][3][r];
        float rot0 = sgn * __shfl_xor(v0, 1);
        float rot1 = sgn * __shfl_xor(v1, 1);
        float rot2 = sgn * __shfl_xor(v2, 1);
        float rot3 = sgn * __shfl_xor(v3, 1);
        float pw = pw0 + (float)r;
        float t2 = pw * invf0, t3 = pw * invf1;
        float rv0 = v0 * c0 + rot0 * s0;
        float rv1 = v1 * c1 + rot1 * s1;
        float rv2 = v2 * __cosf(t2) + rot2 * __sinf(t2);
        float rv3 = v3 * __cosf(t3) + rot3 * __sinf(t3);
        float ss = rv0 * rv0 + rv1 * rv1 + rv2 * rv2 + rv3 * rv3;
        #pragma unroll
        for (int off = 1; off < 16; off <<= 1) ss += __shfl_xor(ss, off);
        float sc = 1.f / (sqrtf(ss) + 1e-6f);
        if (isq) sc *= 0.18033688011112042f;           // log2(e)/8 folded into Q
        bf16* tb = tb0 + r * 8;
        unsigned pkA = cvtpk(rv0 * sc, rv1 * sc);
        unsigned pkB = cvtpk(rv2 * sc, rv3 * sc);
        *(unsigned short*)&tb[0]   = (unsigned short)pkA;
        *(unsigned short*)&tb[256] = (unsigned short)(pkA >> 16);
        *(unsigned short*)&tb[512] = (unsigned short)pkB;
        *(unsigned short*)&tb[768] = (unsigned short)(pkB >> 16);
      }
    }
  } else {
    const bool is2 = (bn >= 18);
    bf16* Vp = is2 ? Vpk2 : Vpk1;
    const int kvh_ = (bn - (is2 ? 18 : 16)) * 2 + wn;  // 0..3
    #pragma unroll
    for (int mt = 0; mt < 4; ++mt)
      #pragma unroll
      for (int r = 0; r < 4; ++r) {
        int row = bm * 128 + wm * 64 + mt * 16 + quad * 4 + r;
        int n = row & (NSEQ - 1);
        int bb = row >> 10, kh = n >> 5;
        int rowm = (mt & 1) * 16 + quad * 4 + r;       // key index in 32-tile
        // R16 pi-permuted slot: key = kt*16 + Q*4 + rr -> slot Q*8 + kt*4 + rr
        int quad_v = (rowm >> 2) & 3;
        int j = ((rowm >> 4) << 2) | (rowm & 3);
        bf16* tb = Vp + ((size_t)(bb * 4 + kvh_) * 32 + kh) * 2048
                   + quad_v * 128 + lr * 8 + j;
        unsigned pkA = cvtpk(acc[mt][0][r], acc[mt][1][r]);
        unsigned pkB = cvtpk(acc[mt][2][r], acc[mt][3][r]);
        *(unsigned short*)&tb[0]    = (unsigned short)pkA;
        *(unsigned short*)&tb[512]  = (unsigned short)(pkA >> 16);
        *(unsigned short*)&tb[1024] = (unsigned short)pkB;
        *(unsigned short*)&tb[1536] = (unsigned short)(pkB >> 16);
      }
  }
}

// ---------------------------------------------------------------------------
// Final GEMM: out = X @ Wo^T + bo, f32 out. 64x64 tiles, grid (12,64) = 768
// blocks = 3 blocks/CU. R12 BK=64 version (R14's BK=128 regressed +1 µs).
// 16 KB LDS, both-sides XOR swizzle as gemm_qkv.
// ---------------------------------------------------------------------------
__global__ __launch_bounds__(256) void gemm_out(
    const bf16* __restrict__ Xb, const bf16* __restrict__ Wob,
    float* __restrict__ out, const float* __restrict__ bias)
{
  __shared__ __align__(16) bf16 As[64 * 64];
  __shared__ __align__(16) bf16 Ws[64 * 64];

  const int bn = blockIdx.x, bm = blockIdx.y;
  const int t = threadIdx.x, wave = t >> 6, lane = t & 63;
  const int wm = wave >> 1, wn = wave & 1;
  const int quad = lane >> 4, lr = lane & 15;

  // staging: wave stages 16 rows per tile as 2 chunks of 8 rows x 64 cols,
  // source col group XOR'ed with row&7 (== lane>>3).
  const int srow = wave * 16 + (lane >> 3);
  const int scol = ((lane & 7) ^ (lane >> 3)) * 8;
  const bf16* Ag = Xb  + (size_t)(bm * 64 + srow) * 768 + scol;
  const bf16* Wg = Wob + (size_t)(bn * 64 + srow) * 768 + scol;
  bf16* Al = As + wave * 16 * 64;
  bf16* Wl = Ws + wave * 16 * 64;

  floatx4 acc[2][2] = {};

  for (int k0 = 0; k0 < 768; k0 += 64) {
    #pragma unroll
    for (int c = 0; c < 2; ++c) {
      load_lds_16(Ag + (size_t)c * 8 * 768 + k0, Al + c * 8 * 64);
      load_lds_16(Wg + (size_t)c * 8 * 768 + k0, Wl + c * 8 * 64);
    }
    __syncthreads();

    short8 af[2][2], wf[2][2];
    #pragma unroll
    for (int mt = 0; mt < 2; ++mt)
      #pragma unroll
      for (int ks = 0; ks < 2; ++ks)
        af[mt][ks] = *reinterpret_cast<const short8*>(
            &As[(wm * 32 + mt * 16 + lr) * 64 + ((ks * 32 + quad * 8) ^ ((lr & 7) * 8))]);
    #pragma unroll
    for (int nt = 0; nt < 2; ++nt)
      #pragma unroll
      for (int ks = 0; ks < 2; ++ks)
        wf[nt][ks] = *reinterpret_cast<const short8*>(
            &Ws[(wn * 32 + nt * 16 + lr) * 64 + ((ks * 32 + quad * 8) ^ ((lr & 7) * 8))]);

    #pragma unroll
    for (int mt = 0; mt < 2; ++mt)
      #pragma unroll
      for (int nt = 0; nt < 2; ++nt) {
        acc[mt][nt] = __builtin_amdgcn_mfma_f32_16x16x32_bf16(af[mt][0], wf[nt][0], acc[mt][nt], 0, 0, 0);
        acc[mt][nt] = __builtin_amdgcn_mfma_f32_16x16x32_bf16(af[mt][1], wf[nt][1], acc[mt][nt], 0, 0, 0);
      }
    __syncthreads();
  }

  #pragma unroll
  for (int nt = 0; nt < 2; ++nt) {
    int col = bn * 64 + wn * 32 + nt * 16 + lr;
    float bv = bias[col];
    #pragma unroll
    for (int mt = 0; mt < 2; ++mt)
      #pragma unroll
      for (int r = 0; r < 4; ++r) {
        int row = bm * 64 + wm * 32 + mt * 16 + quad * 4 + r;
        out[(size_t)row * 768 + col] = acc[mt][nt][r] + bv;
      }
  }
}

// ---------------------------------------------------------------------------
// MFMA flash attention. R15: swapped QK^T (St = mfma(K,Q)) put P in
// registers. R16: zero-shuffle PV (pi-permuted V rows; PV A-frag = lane's
// own cvt_pk registers) + window mask folded into MFMA acc init.
// R16 post-mortem: neutral vs R15 -> attn inner loop is MFMA/load-latency
// floor-limited; op-dieting exhausted. Structure frozen.
// ---------------------------------------------------------------------------
struct Frag { short8 kf[2][2]; short8 vf[4]; };

__device__ __forceinline__ void attn_load(
    Frag& f, const bf16* __restrict__ kp, const bf16* __restrict__ vp,
    int kh, int lane8)
{
  const bf16* kt = kp + (size_t)kh * 2048 + lane8;
  const bf16* vt = vp + (size_t)kh * 2048 + lane8;
  f.kf[0][0] = *reinterpret_cast<const short8*>(kt);
  f.kf[0][1] = *reinterpret_cast<const short8*>(kt + 512);
  f.kf[1][0] = *reinterpret_cast<const short8*>(kt + 1024);
  f.kf[1][1] = *reinterpret_cast<const short8*>(kt + 1536);
  f.vf[0] = *reinterpret_cast<const short8*>(vt);
  f.vf[1] = *reinterpret_cast<const short8*>(vt + 512);
  f.vf[2] = *reinterpret_cast<const short8*>(vt + 1024);
  f.vf[3] = *reinterpret_cast<const short8*>(vt + 1536);
}

__device__ __forceinline__ void attn_step(
    const short8 (&qf)[2][2], const Frag& f, const floatx4 (&Sinit)[2][2],
    floatx4 (&O)[2][4], float (&psum)[2])
{
  // Swapped: St[kt][mt] = K_kt * Q_mt^T -> D[key-local][q-local].
  // Mask pre-loaded into the accumulator (0 or -1e38).
  floatx4 St[2][2] = {{Sinit[0][0], Sinit[0][1]}, {Sinit[1][0], Sinit[1][1]}};
  #pragma unroll
  for (int ks = 0; ks < 2; ++ks) {
    St[0][0] = __builtin_amdgcn_mfma_f32_16x16x32_bf16(f.kf[0][ks], qf[0][ks], St[0][0], 0, 0, 0);
    St[0][1] = __builtin_amdgcn_mfma_f32_16x16x32_bf16(f.kf[0][ks], qf[1][ks], St[0][1], 0, 0, 0);
    St[1][0] = __builtin_amdgcn_mfma_f32_16x16x32_bf16(f.kf[1][ks], qf[0][ks], St[1][0], 0, 0, 0);
    St[1][1] = __builtin_amdgcn_mfma_f32_16x16x32_bf16(f.kf[1][ks], qf[1][ks], St[1][1], 0, 0, 0);
  }

  // softmax weights (S carries 0.125*log2(e) via Q pack): weight = exp2(S);
  // masked entries are exp2(-1e38) = 0 exactly.
  unsigned pk[2][2][2];
  #pragma unroll
  for (int kt = 0; kt < 2; ++kt)
    #pragma unroll
    for (int mt = 0; mt < 2; ++mt) {
      float pr[4];
      #pragma unroll
      for (int r = 0; r < 4; ++r) {
        float p = __builtin_amdgcn_exp2f(St[kt][mt][r]);
        psum[mt] += p;
        pr[r] = p;
      }
      pk[kt][mt][0] = cvtpk(pr[0], pr[1]);
      pk[kt][mt][1] = cvtpk(pr[2], pr[3]);
    }

  // PV A-frag: with pi-permuted V rows, A-slot j = key (j>=4?16:0)+quad*4+(j&3)
  // -> the lane's own pk registers, in order. Zero cross-lane ops.
  #pragma unroll
  for (int mt = 0; mt < 2; ++mt) {
    uint4v regs;
    regs[0] = pk[0][mt][0];
    regs[1] = pk[0][mt][1];
    regs[2] = pk[1][mt][0];
    regs[3] = pk[1][mt][1];
    short8 pa = __builtin_bit_cast(short8, regs);
    #pragma unroll
    for (int ntd = 0; ntd < 4; ++ntd)
      O[mt][ntd] = __builtin_amdgcn_mfma_f32_16x16x32_bf16(pa, f.vf[ntd], O[mt][ntd], 0, 0, 0);
  }
}

__global__ __launch_bounds__(256, 2) void attn_mfma(
    const bf16* __restrict__ Qpk, const bf16* __restrict__ Kpk,
    const bf16* __restrict__ Vpk1, const bf16* __restrict__ Vpk2,
    const float* __restrict__ lambda_p, bf16* __restrict__ X)
{
  // Combine phase: slabA [0,10240) = O 8192 + psum (stream 0)
  //                slabB [10240,20480)                (stream 1)
  //                Xs [0,4608) after B3 (slabA dead by then)
  __shared__ __align__(16) char smem[20480];

  const int bid = blockIdx.x;
  const int qh = bid & 31;
  const int hb = bid >> 5;          // h + 12*b
  const int h  = hb % 12;
  const int b  = hb / 12;
  const int kvh = h / 3;

  const int t = threadIdx.x;
  const int w = t >> 6;             // 0..3
  const int s = w >> 1;             // stream
  const int half = w & 1;           // kh half
  const int lane = t & 63;
  const int quad = lane >> 4, lr = lane & 15;
  const int lane8 = lane * 8;

  float* myO = (float*)(smem + (s ? 10240 : 0));        // this stream's slab
  float* myP = (float*)(smem + (s ? 10240 : 0) + 8192);
  bf16* Xs = (bf16*)smem;                               // [32][72] bf16

  const int tok0 = b * NSEQ + qh * 32;

  // Q fragments: coalesced from packed tiles
  short8 qf[2][2];
  {
    const bf16* qt = Qpk + ((size_t)((b * 2 + s) * 12 + h) * 32 + qh) * 2048 + lane8;
    qf[0][0] = *reinterpret_cast<const short8*>(qt);
    qf[0][1] = *reinterpret_cast<const short8*>(qt + 512);
    qf[1][0] = *reinterpret_cast<const short8*>(qt + 1024);
    qf[1][1] = *reinterpret_cast<const short8*>(qt + 1536);
  }

  // window mask folded into MFMA acc init (swapped layout):
  // key w = kt*16+quad*4+r, q w = mt*16+lr; masked iff |dw| > 8.
  floatx4 Sinit[2][2];
  #pragma unroll
  for (int kt = 0; kt < 2; ++kt)
    #pragma unroll
    for (int mt = 0; mt < 2; ++mt)
      #pragma unroll
      for (int r = 0; r < 4; ++r) {
        int wk = kt * 16 + quad * 4 + r;
        int wq = mt * 16 + lr;
        int d = wk - wq; if (d < 0) d = -d;
        Sinit[kt][mt][r] = (d <= 8) ? 0.0f : -1e38f;
      }

  floatx4 O[2][4] = {};
  float psum[2] = {};

  const int kh0 = (qh > 8) ? qh - 8 : 0;
  const int kh1 = (qh < 23) ? qh + 8 : 31;
  const int cnt = kh1 - kh0 + 1;              // 9..17 -> both halves nonempty
  const int cA = (cnt + 1) >> 1;
  const int khA = half ? kh0 + cA : kh0;
  const int khB = half ? kh1 : kh0 + cA - 1;

  const bf16* kpbase = Kpk + (size_t)((b * 2 + s) * 4 + kvh) * 32 * 2048;
  const bf16* vpbase = (s ? Vpk2 : Vpk1) + (size_t)(b * 4 + kvh) * 32 * 2048;

  Frag fA, fB;
  attn_load(fA, kpbase, vpbase, khA, lane8);
  attn_load(fB, kpbase, vpbase, (khA + 1 <= khB) ? khA + 1 : khB, lane8);

  int i = khA;
  while (true) {
    attn_step(qf, fA, Sinit, O, psum);
    if (i == khB) break;
    ++i;
    attn_load(fA, kpbase, vpbase, (i + 1 <= khB) ? i + 1 : i, lane8);
    attn_step(qf, fB, Sinit, O, psum);
    if (i == khB) break;
    ++i;
    attn_load(fB, kpbase, vpbase, (i + 1 <= khB) ? i + 1 : i, lane8);
  }

  // ---- parallel two-stream combine (each stream in its own slab) ----
  auto writeslab = [&]() {
    #pragma unroll
    for (int mt = 0; mt < 2; ++mt)
      #pragma unroll
      for (int ntd = 0; ntd < 4; ++ntd)
        *reinterpret_cast<floatx4*>(&myO[(mt * 4 + ntd) * 256 + lane * 4]) = O[mt][ntd];
    myP[lane]      = psum[0];
    myP[64 + lane] = psum[1];
  };
  auto readadd_norm = [&]() {
    #pragma unroll
    for (int mt = 0; mt < 2; ++mt)
      #pragma unroll
      for (int ntd = 0; ntd < 4; ++ntd)
        O[mt][ntd] += *reinterpret_cast<const floatx4*>(&myO[(mt * 4 + ntd) * 256 + lane * 4]);
    psum[0] += myP[lane];
    psum[1] += myP[64 + lane];
    // cross-quad reduce: lanes {l, l^16, l^32, l^48} hold the 4 quad partials
    // for q = mt*16 + lr -> after xor16+xor32, fully reduced and replicated.
    #pragma unroll
    for (int mt = 0; mt < 2; ++mt) {
      psum[mt] += __shfl_xor(psum[mt], 16);
      psum[mt] += __shfl_xor(psum[mt], 32);
      psum[mt] = 1.f / psum[mt];
    }
    // remap inverse onto O rows (q = mt*16 + quad*4 + r): fetch from the
    // lane in own quad with lr' = quad*4 + r (value replicated over quads).
    #pragma unroll
    for (int mt = 0; mt < 2; ++mt) {
      float invq[4];
      #pragma unroll
      for (int r = 0; r < 4; ++r)
        invq[r] = __shfl(psum[mt], (lane & 48) + quad * 4 + r);
      #pragma unroll
      for (int ntd = 0; ntd < 4; ++ntd)
        #pragma unroll
        for (int r = 0; r < 4; ++r)
          O[mt][ntd][r] *= invq[r];
    }
  };

  __syncthreads();                       // B1: loop done
  if (half) writeslab();                 // w1 -> slabA, w3 -> slabB
  __syncthreads();                       // B2
  if (!half) {
    readadd_norm();                      // w0: stream0 total; w2: stream1 total
    if (s) {                             // w2 publishes normalized O2
      #pragma unroll
      for (int mt = 0; mt < 2; ++mt)
        #pragma unroll
        for (int ntd = 0; ntd < 4; ++ntd)
          *reinterpret_cast<floatx4*>(&myO[(mt * 4 + ntd) * 256 + lane * 4]) = O[mt][ntd];
    }
  }
  __syncthreads();                       // B3
  if (w == 0) {                          // differential combine -> Xs
    const float* O2s = (const float*)(smem + 10240);
    float lam = log1pf(__expf(lambda_p[h]));
    #pragma unroll
    for (int mt = 0; mt < 2; ++mt)
      #pragma unroll
      for (int ntd = 0; ntd < 4; ++ntd) {
        floatx4 o2 = *reinterpret_cast<const floatx4*>(&O2s[(mt * 4 + ntd) * 256 + lane * 4]);
        #pragma unroll
        for (int r = 0; r < 4; ++r) {
          float xv = O[mt][ntd][r] - lam * o2[r];
          *(unsigned short*)&Xs[(mt * 16 + quad * 4 + r) * 72 + ntd * 16 + lr] = f2b(xv);
        }
      }
  }
  __syncthreads();                       // B4

  // coalesced store of the 32x64 bf16 tile (256 thr = 32 rows x 8 segs)
  {
    int row = t >> 3, seg = t & 7;
    short8 xv = *reinterpret_cast<const short8*>(&Xs[row * 72 + seg * 8]);
    *reinterpret_cast<short8*>(X + (size_t)(tok0 + row) * 768 + h * 64 + seg * 8) = xv;
  }
}

// ---------------------------------------------------------------------------
extern "C" void kernel_launch(void* const* d_in, const int* in_sizes, int n_in,
                              void* d_out, int out_size, void* d_ws, size_t ws_size,
                              hipStream_t stream)
{
  const float* x        = (const float*)d_in[0];
  const float* Wq       = (const float*)d_in[1];
  const float* Wk       = (const float*)d_in[2];
  const float* Wv1      = (const float*)d_in[3];
  const float* Wv2      = (const float*)d_in[4];
  const float* lambda_p = (const float*)d_in[5];
  const float* Wo       = (const float*)d_in[6];
  const float* bo       = (const float*)d_in[7];
  float* out = (float*)d_out;

  bf16* xb   = (bf16*)d_ws;                      // 4096*768
  bf16* Wqb  = xb   + (size_t)NTOK * 768;        // 1536*768
  bf16* Wkb  = Wqb  + (size_t)1536 * 768;        // 512*768
  bf16* Wv1b = Wkb  + (size_t)512 * 768;         // 256*768
  bf16* Wv2b = Wv1b + (size_t)256 * 768;         // 256*768
  bf16* Wob  = Wv2b + (size_t)256 * 768;         // 768*768
  bf16* Qpk  = Wob  + (size_t)768 * 768;         // 3072 tiles * 2048
  bf16* Xb   = Qpk  + (size_t)NTOK * 1536;       // 4096*768
  bf16* Vpk1 = Xb   + (size_t)NTOK * 768;        // 512 tiles * 2048
  bf16* Vpk2 = Vpk1 + (size_t)512 * 2048;        // 512 tiles * 2048
  bf16* Kpk  = Vpk2 + (size_t)512 * 2048;        // 1024 tiles * 2048

  cvt_all<<<5568, 256, 0, stream>>>(x, Wq, Wk, Wv1, Wv2, Wo,
                                    xb, Wqb, Wkb, Wv1b, Wv2b, Wob);

  gemm_qkv<<<dim3(20, 32), 256, 0, stream>>>(xb, Wqb, Wkb, Wv1b, Wv2b,
                                             Qpk, Kpk, Vpk1, Vpk2);

  attn_mfma<<<BATCH * NH * 32, 256, 0, stream>>>(Qpk, Kpk, Vpk1, Vpk2, lambda_p, Xb);

  gemm_out<<<dim3(12, 64), 256, 0, stream>>>(Xb, Wob, out, bo);
}

// Round 8
// 140.413 us; speedup vs baseline: 1.0324x; 1.0199x over previous
//
#include <hip/hip_runtime.h>
#include <hip/hip_bf16.h>

// Sizes fixed by the problem
#define BATCH 4
#define NSEQ  1024
#define DIM   768
#define NH    12
#define NKV   4
#define HD    64
#define NTOK  (BATCH*NSEQ)   // 4096

using bf16 = __hip_bfloat16;
typedef __attribute__((ext_vector_type(8))) short short8;
typedef __attribute__((ext_vector_type(4))) float floatx4;
typedef __attribute__((ext_vector_type(4))) unsigned uint4v;

__device__ __forceinline__ float b2f(short x) {
  unsigned u = ((unsigned)(unsigned short)x) << 16;
  return __builtin_bit_cast(float, u);
}
__device__ __forceinline__ unsigned short f2b(float f) {
  unsigned u = __builtin_bit_cast(unsigned, f);
  unsigned r = u + 0x7FFF + ((u >> 16) & 1);   // RNE
  return (unsigned short)(r >> 16);
}
// packed f32x2 -> bf16x2 (RNE), single VALU op. lo -> bits[15:0], hi -> [31:16]
__device__ __forceinline__ unsigned cvtpk(float lo, float hi) {
  unsigned r;
  asm("v_cvt_pk_bf16_f32 %0, %1, %2" : "=v"(r) : "v"(lo), "v"(hi));
  return r;
}

// async global->LDS, 16B per lane; LDS dest = wave-uniform base + lane*16
__device__ __forceinline__ void load_lds_16(const bf16* g, bf16* l) {
  __builtin_amdgcn_global_load_lds(
      (const __attribute__((address_space(1))) void*)g,
      (__attribute__((address_space(3))) void*)l, 16, 0, 0);
}

// ---------------------------------------------------------------------------
// Fused f32->bf16 convert of all 6 input tensors (exact sizes hardcoded).
// ---------------------------------------------------------------------------
__global__ __launch_bounds__(256) void cvt_all(
    const float* __restrict__ x,  const float* __restrict__ wq,
    const float* __restrict__ wk, const float* __restrict__ wv1,
    const float* __restrict__ wv2, const float* __restrict__ wo,
    bf16* __restrict__ xb,  bf16* __restrict__ wqb, bf16* __restrict__ wkb,
    bf16* __restrict__ wv1b, bf16* __restrict__ wv2b, bf16* __restrict__ wob)
{
  int i = blockIdx.x * 256 + threadIdx.x;   // float4 index, total 1425408
  const float* s; bf16* d; int off;
  if      (i <  786432) { s = x;   d = xb;   off = i; }
  else if (i < 1081344) { s = wq;  d = wqb;  off = i -  786432; }
  else if (i < 1179648) { s = wk;  d = wkb;  off = i - 1081344; }
  else if (i < 1228800) { s = wv1; d = wv1b; off = i - 1179648; }
  else if (i < 1277952) { s = wv2; d = wv2b; off = i - 1228800; }
  else                  { s = wo;  d = wob;  off = i - 1277952; }
  float4 f = reinterpret_cast<const float4*>(s)[off];
  ushort4 u;
  u.x = f2b(f.x); u.y = f2b(f.y); u.z = f2b(f.z); u.w = f2b(f.w);
  reinterpret_cast<ushort4*>(d)[off] = u;
}

// ---------------------------------------------------------------------------
// Fused QKV projection GEMM, 128x128 tile, BK=64 (R12). LDS 32 KB.
// Both-sides XOR swizzle (rule 21). grid = (20 N-tiles, 32 M-tiles).
// N-tiles 0-11: q (rope+norm -> PACKED Qpk), 12-15: k (-> Kpk),
// 16-17: v1, 18-19: v2 (-> pi-permuted Vpk, R16).
// R17: __launch_bounds__(256,3) — kept (>= R16; 640-block tail argument).
// R11 epilogue diet retained. Epilogue rule: no pointer-arg calls (R4 bug).
// ---------------------------------------------------------------------------
__global__ __launch_bounds__(256, 3) void gemm_qkv(
    const bf16* __restrict__ xb,
    const bf16* __restrict__ Wqb, const bf16* __restrict__ Wkb,
    const bf16* __restrict__ Wv1b, const bf16* __restrict__ Wv2b,
    bf16* __restrict__ Qpk, bf16* __restrict__ Kpk,
    bf16* __restrict__ Vpk1, bf16* __restrict__ Vpk2)
{
  __shared__ __align__(16) bf16 As[128 * 64];
  __shared__ __align__(16) bf16 Ws[128 * 64];

  const int bn = blockIdx.x, bm = blockIdx.y;
  const bf16* Wp;
  if (bn < 12)      Wp = Wqb  + (size_t)bn * 128 * 768;
  else if (bn < 16) Wp = Wkb  + (size_t)(bn - 12) * 128 * 768;
  else if (bn < 18) Wp = Wv1b + (size_t)(bn - 16) * 128 * 768;
  else              Wp = Wv2b + (size_t)(bn - 18) * 128 * 768;

  const int t = threadIdx.x, wave = t >> 6, lane = t & 63;
  const int wm = wave >> 1, wn = wave & 1;
  const int quad = lane >> 4, lr = lane & 15;

  // staging: wave stages 32 rows per tile as 4 chunks of 8 rows x 64 cols.
  // chunk row = wave*32 + c*8 + (lane>>3)  (row&7 == lane>>3), source col
  // group XOR'ed with row&7 so linear LDS dest lands swizzled.
  const int srow = wave * 32 + (lane >> 3);
  const int scol = ((lane & 7) ^ (lane >> 3)) * 8;
  const bf16* Ag = xb + (size_t)(bm * 128 + srow) * 768 + scol;
  const bf16* Wg = Wp + (size_t)srow * 768 + scol;
  bf16* Al = As + wave * 32 * 64;
  bf16* Wl = Ws + wave * 32 * 64;

  floatx4 acc[4][4] = {};

  for (int k0 = 0; k0 < 768; k0 += 64) {
    #pragma unroll
    for (int c = 0; c < 4; ++c) {
      load_lds_16(Ag + (size_t)c * 8 * 768 + k0, Al + c * 8 * 64);
      load_lds_16(Wg + (size_t)c * 8 * 768 + k0, Wl + c * 8 * 64);
    }
    __syncthreads();

    short8 af[4][2], wf[4][2];
    #pragma unroll
    for (int mt = 0; mt < 4; ++mt)
      #pragma unroll
      for (int ks = 0; ks < 2; ++ks)
        af[mt][ks] = *reinterpret_cast<const short8*>(
            &As[(wm * 64 + mt * 16 + lr) * 64 + ((ks * 32 + quad * 8) ^ ((lr & 7) * 8))]);
    #pragma unroll
    for (int nt = 0; nt < 4; ++nt)
      #pragma unroll
      for (int ks = 0; ks < 2; ++ks)
        wf[nt][ks] = *reinterpret_cast<const short8*>(
            &Ws[(wn * 64 + nt * 16 + lr) * 64 + ((ks * 32 + quad * 8) ^ ((lr & 7) * 8))]);

    #pragma unroll
    for (int mt = 0; mt < 4; ++mt)
      #pragma unroll
      for (int nt = 0; nt < 4; ++nt) {
        acc[mt][nt] = __builtin_amdgcn_mfma_f32_16x16x32_bf16(af[mt][0], wf[nt][0], acc[mt][nt], 0, 0, 0);
        acc[mt][nt] = __builtin_amdgcn_mfma_f32_16x16x32_bf16(af[mt][1], wf[nt][1], acc[mt][nt], 0, 0, 0);
      }
    __syncthreads();
  }

  // Epilogues. C/D: row = bm*128 + wm*64 + mt*16 + quad*4 + r,
  //                 col(within 128-tile) = wn*64 + nt*16 + lr
  if (bn < 16) {
    const float K2 = 0.41524101186098309f;             // log2(10000)/32
    const float invf0 = exp2f(-(float)lr * K2);
    const float invf1 = exp2f(-(float)(16 + lr) * K2);
    const float sgn = (lr & 1) ? 1.f : -1.f;
    const bool isq = (bn < 12);
    const int hq = bn * 2 + wn;                        // 0..23 (q)
    const int sq_ = hq / 12, hq_ = hq % 12;
    const int hh = (bn - 12) * 2 + wn;                 // 0..7 (k)
    const int sk_ = hh >> 2, kvh_ = hh & 3;
    const int qk128 = (lr >> 3) * 128;
    #pragma unroll
    for (int mt = 0; mt < 4; ++mt) {
      // row group is 4-aligned -> n>>5, row>>10 constant across r (no cross)
      const int row0 = bm * 128 + wm * 64 + mt * 16 + quad * 4;
      const int n0 = row0 & (NSEQ - 1);
      const int bb = row0 >> 10, kh = n0 >> 5;
      const float ph = (float)kh;
      const float pw0 = (float)(n0 & 31);
      const float t0 = ph * invf0, t1 = ph * invf1;
      const float c0 = __cosf(t0), s0 = __sinf(t0);
      const float c1 = __cosf(t1), s1 = __sinf(t1);
      bf16* tb0;
      if (isq) {
        tb0 = Qpk + ((size_t)((bb * 2 + sq_) * 12 + hq_) * 32 + kh) * 2048
              + (size_t)(mt & 1) * 1024 + qk128 + (quad * 4) * 8 + (lr & 7);
      } else {
        tb0 = Kpk + ((size_t)((bb * 2 + sk_) * 4 + kvh_) * 32 + kh) * 2048
              + (size_t)(mt & 1) * 1024 + qk128 + (quad * 4) * 8 + (lr & 7);
      }
      #pragma unroll
      for (int r = 0; r < 4; ++r) {
        float v0 = acc[mt][0][r];
        float v1 = acc[mt][1][r];
        float v2 = acc[mt][2][r];
        float v3 = acc[mt][3][r];
        float rot0 = sgn * __shfl_xor(v0, 1);
        float rot1 = sgn * __shfl_xor(v1, 1);
        float rot2 = sgn * __shfl_xor(v2, 1);
        float rot3 = sgn * __shfl_xor(v3, 1);
        float pw = pw0 + (float)r;
        float t2 = pw * invf0, t3 = pw * invf1;
        float rv0 = v0 * c0 + rot0 * s0;
        float rv1 = v1 * c1 + rot1 * s1;
        float rv2 = v2 * __cosf(t2) + rot2 * __sinf(t2);
        float rv3 = v3 * __cosf(t3) + rot3 * __sinf(t3);
        float ss = rv0 * rv0 + rv1 * rv1 + rv2 * rv2 + rv3 * rv3;
        #pragma unroll
        for (int off = 1; off < 16; off <<= 1) ss += __shfl_xor(ss, off);
        float sc = 1.f / (sqrtf(ss) + 1e-6f);
        if (isq) sc *= 0.18033688011112042f;           // log2(e)/8 folded into Q
        bf16* tb = tb0 + r * 8;
        unsigned pkA = cvtpk(rv0 * sc, rv1 * sc);
        unsigned pkB = cvtpk(rv2 * sc, rv3 * sc);
        *(unsigned short*)&tb[0]   = (unsigned short)pkA;
        *(unsigned short*)&tb[256] = (unsigned short)(pkA >> 16);
        *(unsigned short*)&tb[512] = (unsigned short)pkB;
        *(unsigned short*)&tb[768] = (unsigned short)(pkB >> 16);
      }
    }
  } else {
    const bool is2 = (bn >= 18);
    bf16* Vp = is2 ? Vpk2 : Vpk1;
    const int kvh_ = (bn - (is2 ? 18 : 16)) * 2 + wn;  // 0..3
    #pragma unroll
    for (int mt = 0; mt < 4; ++mt)
      #pragma unroll
      for (int r = 0; r < 4; ++r) {
        int row = bm * 128 + wm * 64 + mt * 16 + quad * 4 + r;
        int n = row & (NSEQ - 1);
        int bb = row >> 10, kh = n >> 5;
        int rowm = (mt & 1) * 16 + quad * 4 + r;       // key index in 32-tile
        // R16 pi-permuted slot: key = kt*16 + Q*4 + rr -> slot Q*8 + kt*4 + rr
        int quad_v = (rowm >> 2) & 3;
        int j = ((rowm >> 4) << 2) | (rowm & 3);
        bf16* tb = Vp + ((size_t)(bb * 4 + kvh_) * 32 + kh) * 2048
                   + quad_v * 128 + lr * 8 + j;
        unsigned pkA = cvtpk(acc[mt][0][r], acc[mt][1][r]);
        unsigned pkB = cvtpk(acc[mt][2][r], acc[mt][3][r]);
        *(unsigned short*)&tb[0]    = (unsigned short)pkA;
        *(unsigned short*)&tb[512]  = (unsigned short)(pkA >> 16);
        *(unsigned short*)&tb[1024] = (unsigned short)pkB;
        *(unsigned short*)&tb[1536] = (unsigned short)(pkB >> 16);
      }
  }
}

// ---------------------------------------------------------------------------
// Final GEMM: out = X @ Wo^T + bo, f32 out. 64x64 tiles, grid (12,64) = 768
// blocks = 3 blocks/CU. R12 BK=64 version (R14's BK=128 regressed +1 µs).
// 16 KB LDS, both-sides XOR swizzle as gemm_qkv. Roofline note (R18): this
// kernel is ~4-6 µs (LDS-BW model), not a major term — leave alone.
// ---------------------------------------------------------------------------
__global__ __launch_bounds__(256) void gemm_out(
    const bf16* __restrict__ Xb, const bf16* __restrict__ Wob,
    float* __restrict__ out, const float* __restrict__ bias)
{
  __shared__ __align__(16) bf16 As[64 * 64];
  __shared__ __align__(16) bf16 Ws[64 * 64];

  const int bn = blockIdx.x, bm = blockIdx.y;
  const int t = threadIdx.x, wave = t >> 6, lane = t & 63;
  const int wm = wave >> 1, wn = wave & 1;
  const int quad = lane >> 4, lr = lane & 15;

  // staging: wave stages 16 rows per tile as 2 chunks of 8 rows x 64 cols,
  // source col group XOR'ed with row&7 (== lane>>3).
  const int srow = wave * 16 + (lane >> 3);
  const int scol = ((lane & 7) ^ (lane >> 3)) * 8;
  const bf16* Ag = Xb  + (size_t)(bm * 64 + srow) * 768 + scol;
  const bf16* Wg = Wob + (size_t)(bn * 64 + srow) * 768 + scol;
  bf16* Al = As + wave * 16 * 64;
  bf16* Wl = Ws + wave * 16 * 64;

  floatx4 acc[2][2] = {};

  for (int k0 = 0; k0 < 768; k0 += 64) {
    #pragma unroll
    for (int c = 0; c < 2; ++c) {
      load_lds_16(Ag + (size_t)c * 8 * 768 + k0, Al + c * 8 * 64);
      load_lds_16(Wg + (size_t)c * 8 * 768 + k0, Wl + c * 8 * 64);
    }
    __syncthreads();

    short8 af[2][2], wf[2][2];
    #pragma unroll
    for (int mt = 0; mt < 2; ++mt)
      #pragma unroll
      for (int ks = 0; ks < 2; ++ks)
        af[mt][ks] = *reinterpret_cast<const short8*>(
            &As[(wm * 32 + mt * 16 + lr) * 64 + ((ks * 32 + quad * 8) ^ ((lr & 7) * 8))]);
    #pragma unroll
    for (int nt = 0; nt < 2; ++nt)
      #pragma unroll
      for (int ks = 0; ks < 2; ++ks)
        wf[nt][ks] = *reinterpret_cast<const short8*>(
            &Ws[(wn * 32 + nt * 16 + lr) * 64 + ((ks * 32 + quad * 8) ^ ((lr & 7) * 8))]);

    #pragma unroll
    for (int mt = 0; mt < 2; ++mt)
      #pragma unroll
      for (int nt = 0; nt < 2; ++nt) {
        acc[mt][nt] = __builtin_amdgcn_mfma_f32_16x16x32_bf16(af[mt][0], wf[nt][0], acc[mt][nt], 0, 0, 0);
        acc[mt][nt] = __builtin_amdgcn_mfma_f32_16x16x32_bf16(af[mt][1], wf[nt][1], acc[mt][nt], 0, 0, 0);
      }
    __syncthreads();
  }

  #pragma unroll
  for (int nt = 0; nt < 2; ++nt) {
    int col = bn * 64 + wn * 32 + nt * 16 + lr;
    float bv = bias[col];
    #pragma unroll
    for (int mt = 0; mt < 2; ++mt)
      #pragma unroll
      for (int r = 0; r < 4; ++r) {
        int row = bm * 64 + wm * 32 + mt * 16 + quad * 4 + r;
        out[(size_t)row * 768 + col] = acc[mt][nt][r] + bv;
      }
  }
}

// ---------------------------------------------------------------------------
// MFMA flash attention. R15: swapped QK^T. R16: zero-shuffle PV (pi-permuted
// V rows) + mask folded into acc init. R16 post-mortem: inner loop is
// MFMA-issue/load-latency floor-limited.
// R18: latency-hiding bundle — (a) T5 s_setprio(1) around both MFMA
// clusters (m191: +4-7% attn, within-probe; prerequisite wave-role
// diversity holds: 4 independent variable-trip waves, no lockstep barrier);
// (b) __launch_bounds__(256,3): 1536 blocks at 3/CU = 2 dispatch waves
// (was 3) + 50% more co-resident waves for K/V latency hiding. VGPR
// estimate ~156-165 <= 170 cap. If this round regresses >1us, the bound
// is the suspect (Frag dbuf spill) — revert it first, keep setprio.
// ---------------------------------------------------------------------------
struct Frag { short8 kf[2][2]; short8 vf[4]; };

__device__ __forceinline__ void attn_load(
    Frag& f, const bf16* __restrict__ kp, const bf16* __restrict__ vp,
    int kh, int lane8)
{
  const bf16* kt = kp + (size_t)kh * 2048 + lane8;
  const bf16* vt = vp + (size_t)kh * 2048 + lane8;
  f.kf[0][0] = *reinterpret_cast<const short8*>(kt);
  f.kf[0][1] = *reinterpret_cast<const short8*>(kt + 512);
  f.kf[1][0] = *reinterpret_cast<const short8*>(kt + 1024);
  f.kf[1][1] = *reinterpret_cast<const short8*>(kt + 1536);
  f.vf[0] = *reinterpret_cast<const short8*>(vt);
  f.vf[1] = *reinterpret_cast<const short8*>(vt + 512);
  f.vf[2] = *reinterpret_cast<const short8*>(vt + 1024);
  f.vf[3] = *reinterpret_cast<const short8*>(vt + 1536);
}

__device__ __forceinline__ void attn_step(
    const short8 (&qf)[2][2], const Frag& f, const floatx4 (&Sinit)[2][2],
    floatx4 (&O)[2][4], float (&psum)[2])
{
  // Swapped: St[kt][mt] = K_kt * Q_mt^T -> D[key-local][q-local].
  // Mask pre-loaded into the accumulator (0 or -1e38).
  floatx4 St[2][2] = {{Sinit[0][0], Sinit[0][1]}, {Sinit[1][0], Sinit[1][1]}};
  __builtin_amdgcn_s_setprio(1);
  #pragma unroll
  for (int ks = 0; ks < 2; ++ks) {
    St[0][0] = __builtin_amdgcn_mfma_f32_16x16x32_bf16(f.kf[0][ks], qf[0][ks], St[0][0], 0, 0, 0);
    St[0][1] = __builtin_amdgcn_mfma_f32_16x16x32_bf16(f.kf[0][ks], qf[1][ks], St[0][1], 0, 0, 0);
    St[1][0] = __builtin_amdgcn_mfma_f32_16x16x32_bf16(f.kf[1][ks], qf[0][ks], St[1][0], 0, 0, 0);
    St[1][1] = __builtin_amdgcn_mfma_f32_16x16x32_bf16(f.kf[1][ks], qf[1][ks], St[1][1], 0, 0, 0);
  }
  __builtin_amdgcn_s_setprio(0);

  // softmax weights (S carries 0.125*log2(e) via Q pack): weight = exp2(S);
  // masked entries are exp2(-1e38) = 0 exactly.
  unsigned pk[2][2][2];
  #pragma unroll
  for (int kt = 0; kt < 2; ++kt)
    #pragma unroll
    for (int mt = 0; mt < 2; ++mt) {
      float pr[4];
      #pragma unroll
      for (int r = 0; r < 4; ++r) {
        float p = __builtin_amdgcn_exp2f(St[kt][mt][r]);
        psum[mt] += p;
        pr[r] = p;
      }
      pk[kt][mt][0] = cvtpk(pr[0], pr[1]);
      pk[kt][mt][1] = cvtpk(pr[2], pr[3]);
    }

  // PV A-frag: with pi-permuted V rows, A-slot j = key (j>=4?16:0)+quad*4+(j&3)
  // -> the lane's own pk registers, in order. Zero cross-lane ops.
  __builtin_amdgcn_s_setprio(1);
  #pragma unroll
  for (int mt = 0; mt < 2; ++mt) {
    uint4v regs;
    regs[0] = pk[0][mt][0];
    regs[1] = pk[0][mt][1];
    regs[2] = pk[1][mt][0];
    regs[3] = pk[1][mt][1];
    short8 pa = __builtin_bit_cast(short8, regs);
    #pragma unroll
    for (int ntd = 0; ntd < 4; ++ntd)
      O[mt][ntd] = __builtin_amdgcn_mfma_f32_16x16x32_bf16(pa, f.vf[ntd], O[mt][ntd], 0, 0, 0);
  }
  __builtin_amdgcn_s_setprio(0);
}

__global__ __launch_bounds__(256, 3) void attn_mfma(
    const bf16* __restrict__ Qpk, const bf16* __restrict__ Kpk,
    const bf16* __restrict__ Vpk1, const bf16* __restrict__ Vpk2,
    const float* __restrict__ lambda_p, bf16* __restrict__ X)
{
  // Combine phase: slabA [0,10240) = O 8192 + psum (stream 0)
  //                slabB [10240,20480)                (stream 1)
  //                Xs [0,4608) after B3 (slabA dead by then)
  __shared__ __align__(16) char smem[20480];

  const int bid = blockIdx.x;
  const int qh = bid & 31;
  const int hb = bid >> 5;          // h + 12*b
  const int h  = hb % 12;
  const int b  = hb / 12;
  const int kvh = h / 3;

  const int t = threadIdx.x;
  const int w = t >> 6;             // 0..3
  const int s = w >> 1;             // stream
  const int half = w & 1;           // kh half
  const int lane = t & 63;
  const int quad = lane >> 4, lr = lane & 15;
  const int lane8 = lane * 8;

  float* myO = (float*)(smem + (s ? 10240 : 0));        // this stream's slab
  float* myP = (float*)(smem + (s ? 10240 : 0) + 8192);
  bf16* Xs = (bf16*)smem;                               // [32][72] bf16

  const int tok0 = b * NSEQ + qh * 32;

  // Q fragments: coalesced from packed tiles
  short8 qf[2][2];
  {
    const bf16* qt = Qpk + ((size_t)((b * 2 + s) * 12 + h) * 32 + qh) * 2048 + lane8;
    qf[0][0] = *reinterpret_cast<const short8*>(qt);
    qf[0][1] = *reinterpret_cast<const short8*>(qt + 512);
    qf[1][0] = *reinterpret_cast<const short8*>(qt + 1024);
    qf[1][1] = *reinterpret_cast<const short8*>(qt + 1536);
  }

  // window mask folded into MFMA acc init (swapped layout):
  // key w = kt*16+quad*4+r, q w = mt*16+lr; masked iff |dw| > 8.
  floatx4 Sinit[2][2];
  #pragma unroll
  for (int kt = 0; kt < 2; ++kt)
    #pragma unroll
    for (int mt = 0; mt < 2; ++mt)
      #pragma unroll
      for (int r = 0; r < 4; ++r) {
        int wk = kt * 16 + quad * 4 + r;
        int wq = mt * 16 + lr;
        int d = wk - wq; if (d < 0) d = -d;
        Sinit[kt][mt][r] = (d <= 8) ? 0.0f : -1e38f;
      }

  floatx4 O[2][4] = {};
  float psum[2] = {};

  const int kh0 = (qh > 8) ? qh - 8 : 0;
  const int kh1 = (qh < 23) ? qh + 8 : 31;
  const int cnt = kh1 - kh0 + 1;              // 9..17 -> both halves nonempty
  const int cA = (cnt + 1) >> 1;
  const int khA = half ? kh0 + cA : kh0;
  const int khB = half ? kh1 : kh0 + cA - 1;

  const bf16* kpbase = Kpk + (size_t)((b * 2 + s) * 4 + kvh) * 32 * 2048;
  const bf16* vpbase = (s ? Vpk2 : Vpk1) + (size_t)(b * 4 + kvh) * 32 * 2048;

  Frag fA, fB;
  attn_load(fA, kpbase, vpbase, khA, lane8);
  attn_load(fB, kpbase, vpbase, (khA + 1 <= khB) ? khA + 1 : khB, lane8);

  int i = khA;
  while (true) {
    attn_step(qf, fA, Sinit, O, psum);
    if (i == khB) break;
    ++i;
    attn_load(fA, kpbase, vpbase, (i + 1 <= khB) ? i + 1 : i, lane8);
    attn_step(qf, fB, Sinit, O, psum);
    if (i == khB) break;
    ++i;
    attn_load(fB, kpbase, vpbase, (i + 1 <= khB) ? i + 1 : i, lane8);
  }

  // ---- parallel two-stream combine (each stream in its own slab) ----
  auto writeslab = [&]() {
    #pragma unroll
    for (int mt = 0; mt < 2; ++mt)
      #pragma unroll
      for (int ntd = 0; ntd < 4; ++ntd)
        *reinterpret_cast<floatx4*>(&myO[(mt * 4 + ntd) * 256 + lane * 4]) = O[mt][ntd];
    myP[lane]      = psum[0];
    myP[64 + lane] = psum[1];
  };
  auto readadd_norm = [&]() {
    #pragma unroll
    for (int mt = 0; mt < 2; ++mt)
      #pragma unroll
      for (int ntd = 0; ntd < 4; ++ntd)
        O[mt][ntd] += *reinterpret_cast<const floatx4*>(&myO[(mt * 4 + ntd) * 256 + lane * 4]);
    psum[0] += myP[lane];
    psum[1] += myP[64 + lane];
    // cross-quad reduce: lanes {l, l^16, l^32, l^48} hold the 4 quad partials
    // for q = mt*16 + lr -> after xor16+xor32, fully reduced and replicated.
    #pragma unroll
    for (int mt = 0; mt < 2; ++mt) {
      psum[mt] += __shfl_xor(psum[mt], 16);
      psum[mt] += __shfl_xor(psum[mt], 32);
      psum[mt] = 1.f / psum[mt];
    }
    // remap inverse onto O rows (q = mt*16 + quad*4 + r): fetch from the
    // lane in own quad with lr' = quad*4 + r (value replicated over quads).
    #pragma unroll
    for (int mt = 0; mt < 2; ++mt) {
      float invq[4];
      #pragma unroll
      for (int r = 0; r < 4; ++r)
        invq[r] = __shfl(psum[mt], (lane & 48) + quad * 4 + r);
      #pragma unroll
      for (int ntd = 0; ntd < 4; ++ntd)
        #pragma unroll
        for (int r = 0; r < 4; ++r)
          O[mt][ntd][r] *= invq[r];
    }
  };

  __syncthreads();                       // B1: loop done
  if (half) writeslab();                 // w1 -> slabA, w3 -> slabB
  __syncthreads();                       // B2
  if (!half) {
    readadd_norm();                      // w0: stream0 total; w2: stream1 total
    if (s) {                             // w2 publishes normalized O2
      #pragma unroll
      for (int mt = 0; mt < 2; ++mt)
        #pragma unroll
        for (int ntd = 0; ntd < 4; ++ntd)
          *reinterpret_cast<floatx4*>(&myO[(mt * 4 + ntd) * 256 + lane * 4]) = O[mt][ntd];
    }
  }
  __syncthreads();                       // B3
  if (w == 0) {                          // differential combine -> Xs
    const float* O2s = (const float*)(smem + 10240);
    float lam = log1pf(__expf(lambda_p[h]));
    #pragma unroll
    for (int mt = 0; mt < 2; ++mt)
      #pragma unroll
      for (int ntd = 0; ntd < 4; ++ntd) {
        floatx4 o2 = *reinterpret_cast<const floatx4*>(&O2s[(mt * 4 + ntd) * 256 + lane * 4]);
        #pragma unroll
        for (int r = 0; r < 4; ++r) {
          float xv = O[mt][ntd][r] - lam * o2[r];
          *(unsigned short*)&Xs[(mt * 16 + quad * 4 + r) * 72 + ntd * 16 + lr] = f2b(xv);
        }
      }
  }
  __syncthreads();                       // B4

  // coalesced store of the 32x64 bf16 tile (256 thr = 32 rows x 8 segs)
  {
    int row = t >> 3, seg = t & 7;
    short8 xv = *reinterpret_cast<const short8*>(&Xs[row * 72 + seg * 8]);
    *reinterpret_cast<short8*>(X + (size_t)(tok0 + row) * 768 + h * 64 + seg * 8) = xv;
  }
}

// ---------------------------------------------------------------------------
extern "C" void kernel_launch(void* const* d_in, const int* in_sizes, int n_in,
                              void* d_out, int out_size, void* d_ws, size_t ws_size,
                              hipStream_t stream)
{
  const float* x        = (const float*)d_in[0];
  const float* Wq       = (const float*)d_in[1];
  const float* Wk       = (const float*)d_in[2];
  const float* Wv1      = (const float*)d_in[3];
  const float* Wv2      = (const float*)d_in[4];
  const float* lambda_p = (const float*)d_in[5];
  const float* Wo       = (const float*)d_in[6];
  const float* bo       = (const float*)d_in[7];
  float* out = (float*)d_out;

  bf16* xb   = (bf16*)d_ws;                      // 4096*768
  bf16* Wqb  = xb   + (size_t)NTOK * 768;        // 1536*768
  bf16* Wkb  = Wqb  + (size_t)1536 * 768;        // 512*768
  bf16* Wv1b = Wkb  + (size_t)512 * 768;         // 256*768
  bf16* Wv2b = Wv1b + (size_t)256 * 768;         // 256*768
  bf16* Wob  = Wv2b + (size_t)256 * 768;         // 768*768
  bf16* Qpk  = Wob  + (size_t)768 * 768;         // 3072 tiles * 2048
  bf16* Xb   = Qpk  + (size_t)NTOK * 1536;       // 4096*768
  bf16* Vpk1 = Xb   + (size_t)NTOK * 768;        // 512 tiles * 2048
  bf16* Vpk2 = Vpk1 + (size_t)512 * 2048;        // 512 tiles * 2048
  bf16* Kpk  = Vpk2 + (size_t)512 * 2048;        // 1024 tiles * 2048

  cvt_all<<<5568, 256, 0, stream>>>(x, Wq, Wk, Wv1, Wv2, Wo,
                                    xb, Wqb, Wkb, Wv1b, Wv2b, Wob);

  gemm_qkv<<<dim3(20, 32), 256, 0, stream>>>(xb, Wqb, Wkb, Wv1b, Wv2b,
                                             Qpk, Kpk, Vpk1, Vpk2);

  attn_mfma<<<BATCH * NH * 32, 256, 0, stream>>>(Qpk, Kpk, Vpk1, Vpk2, lambda_p, Xb);

  gemm_out<<<dim3(12, 64), 256, 0, stream>>>(Xb, Wob, out, bo);
}